// Round 9
// baseline (739.420 us; speedup 1.0000x reference)
//
#include <hip/hip_runtime.h>
#include <hip/hip_bf16.h>
#include <math.h>

#define N_NODES 50000
#define N_EDGES 1000000
#define D 64
#define ED 16
#define NEG 0.2f

__device__ __forceinline__ float wave_sum(float v) {
  #pragma unroll
  for (int m = 32; m >= 1; m >>= 1) v += __shfl_xor(v, m, 64);
  return v;
}
__device__ __forceinline__ float wave_max(float v) {
  #pragma unroll
  for (int m = 32; m >= 1; m >>= 1) v = fmaxf(v, __shfl_xor(v, m, 64));
  return v;
}

// ---- zero the histogram counters ----
__global__ void k_init(int* __restrict__ cursor) {
  int i = blockIdx.x * 256 + threadIdx.x;
  if (i < N_NODES) cursor[i] = 0;
}

// ---- x_l = x@Wl + bl ; x_r = x@Wr + br (wave per row, lane = out channel) ----
__global__ __launch_bounds__(256) void k_transform(
    const float* __restrict__ x,
    const float* __restrict__ Wl, const float* __restrict__ bl,
    const float* __restrict__ Wr, const float* __restrict__ br,
    float* __restrict__ xl, float* __restrict__ xr) {
  __shared__ float sW[2 * D * D];  // 32 KiB
  float* sWl = sW;
  float* sWr = sW + D * D;
  int t = threadIdx.x;
  for (int q = t; q < D * D / 4; q += 256) {
    ((float4*)sWl)[q] = ((const float4*)Wl)[q];
    ((float4*)sWr)[q] = ((const float4*)Wr)[q];
  }
  __syncthreads();
  int lane = t & 63;
  int row = blockIdx.x * 4 + (t >> 6);
  if (row >= N_NODES) return;
  float xv = x[row * D + lane];
  float accl = bl[lane], accr = br[lane];
  #pragma unroll
  for (int k = 0; k < D; k++) {
    float xk = __shfl(xv, k, 64);
    accl = fmaf(xk, sWl[k * D + lane], accl);
    accr = fmaf(xk, sWr[k * D + lane], accr);
  }
  xl[row * D + lane] = accl;
  xr[row * D + lane] = accr;
}

// ---- per-edge attention logit, ORIGINAL edge order (wave per edge) ----
// Inner math identical to the validated round-1 kernel; only the edge-id
// source changed (direct j instead of perm-array indirection), so ea/ei
// stream linearly.
__global__ __launch_bounds__(256) void k_logits(
    const float* __restrict__ ea, const float* __restrict__ We,
    const float* __restrict__ att,
    const float* __restrict__ xl, const float* __restrict__ xr,
    const int* __restrict__ ei, float* __restrict__ logits) {
  __shared__ float sWe[ED * D];  // 4 KiB
  __shared__ float satt[D];
  int t = threadIdx.x;
  for (int q = t; q < ED * D / 4; q += 256) ((float4*)sWe)[q] = ((const float4*)We)[q];
  if (t < D) satt[t] = att[t];
  __syncthreads();
  int j = blockIdx.x * 4 + (t >> 6);   // 250000 blocks * 4 = 1M exactly
  int lane = t & 63;
  int s = __builtin_amdgcn_readfirstlane(ei[j]);
  int d = __builtin_amdgcn_readfirstlane(ei[N_EDGES + j]);
  // issue the two L2 gathers early so they're in flight under the FMA loop
  float xlv = xl[(size_t)s * D + lane];
  float xrv = xr[(size_t)d * D + lane];
  float eav = (lane < ED) ? ea[(size_t)j * ED + lane] : 0.f;
  float acc = 0.f;
  #pragma unroll
  for (int k = 0; k < ED; k++) {
    float ek = __shfl(eav, k, 64);
    acc = fmaf(ek, sWe[k * D + lane], acc);
  }
  float h = xlv + xrv + acc;
  h = (h > 0.f) ? h : NEG * h;
  float v = wave_sum(h * satt[lane]);
  if (lane == 0) logits[j] = v;
}

// ---- histogram of dst ----
__global__ void k_hist(const int* __restrict__ ei, int* __restrict__ cursor) {
  int e = blockIdx.x * 256 + threadIdx.x;
  if (e < N_EDGES) atomicAdd(&cursor[ei[N_EDGES + e]], 1);
}

// ---- 3-kernel exclusive scan of counts -> row_start ----
__global__ void k_scan_a(const int* __restrict__ counts, int* __restrict__ row_start,
                         int* __restrict__ bsum) {
  __shared__ int sb[256];
  int t = threadIdx.x;
  int i = blockIdx.x * 256 + t;
  int v = (i < N_NODES) ? counts[i] : 0;
  sb[t] = v;
  __syncthreads();
  for (int off = 1; off < 256; off <<= 1) {
    int add = (t >= off) ? sb[t - off] : 0;
    __syncthreads();
    sb[t] += add;
    __syncthreads();
  }
  if (i < N_NODES) row_start[i] = sb[t] - v;  // exclusive
  if (t == 255) bsum[blockIdx.x] = sb[t];
}
__global__ void k_scan_b(int* __restrict__ bsum, int nb) {
  __shared__ int sb[256];
  int t = threadIdx.x;
  int v = (t < nb) ? bsum[t] : 0;
  sb[t] = v;
  __syncthreads();
  for (int off = 1; off < 256; off <<= 1) {
    int add = (t >= off) ? sb[t - off] : 0;
    __syncthreads();
    sb[t] += add;
    __syncthreads();
  }
  if (t < nb) bsum[t] = sb[t] - v;  // exclusive
}
__global__ void k_scan_c(int* __restrict__ row_start, const int* __restrict__ bsum,
                         int* __restrict__ cursor) {
  int t = threadIdx.x;
  int i = blockIdx.x * 256 + t;
  if (i < N_NODES) {
    int r = row_start[i] + bsum[blockIdx.x];
    row_start[i] = r;
    cursor[i] = r;
  }
  if (i == 0) row_start[N_NODES] = N_EDGES;
}

// ---- counting-sort scatter: slot assignment per edge (validated 3-array form,
//      dst_perm dropped — nothing read it) ----
__global__ void k_scatter(const int* __restrict__ ei, int* __restrict__ cursor,
                          int* __restrict__ eid_perm, int* __restrict__ src_perm) {
  int e = blockIdx.x * 256 + threadIdx.x;
  if (e >= N_EDGES) return;
  int s = ei[e];
  int d = ei[N_EDGES + e];
  int pos = atomicAdd(&cursor[d], 1);
  eid_perm[pos] = e;
  src_perm[pos] = s;
}

// ---- permute logits into dst-grouped order (gather from L2-resident 4MB) ----
__global__ void k_permlog(const float* __restrict__ logits,
                          const int* __restrict__ eid_perm,
                          float* __restrict__ plog) {
  int i = blockIdx.x * 256 + threadIdx.x;
  if (i < N_EDGES) plog[i] = logits[eid_perm[i]];
}

// ---- per-node segment softmax + weighted aggregation (wave per node) ----
// Verbatim validated round-1 kernel; logits -> plog (same linear access).
__global__ __launch_bounds__(256) void k_agg(
    const float* __restrict__ plog, const int* __restrict__ row_start,
    const int* __restrict__ src_perm, const float* __restrict__ xl,
    const float* __restrict__ bias, float* __restrict__ out) {
  int t = threadIdx.x;
  int lane = t & 63;
  int row = blockIdx.x * 4 + (t >> 6);
  if (row >= N_NODES) return;
  int start = row_start[row];
  int end = row_start[row + 1];

  float mx = -INFINITY;
  for (int j = start + lane; j < end; j += 64) mx = fmaxf(mx, plog[j]);
  mx = wave_max(mx);

  float sm = 0.f;
  for (int j = start + lane; j < end; j += 64) sm += __expf(plog[j] - mx);
  sm = wave_sum(sm);
  float inv = 1.f / (sm + 1e-16f);

  // 2-way unrolled weighted gather-accumulate (independent chains -> 2 loads in flight)
  float acc0 = 0.f, acc1 = 0.f;
  int j = start;
  for (; j + 1 < end; j += 2) {
    float a0 = __expf(plog[j] - mx) * inv;
    float a1 = __expf(plog[j + 1] - mx) * inv;
    int s0 = __builtin_amdgcn_readfirstlane(src_perm[j]);
    int s1 = __builtin_amdgcn_readfirstlane(src_perm[j + 1]);
    acc0 = fmaf(a0, xl[(size_t)s0 * D + lane], acc0);
    acc1 = fmaf(a1, xl[(size_t)s1 * D + lane], acc1);
  }
  if (j < end) {
    float a0 = __expf(plog[j] - mx) * inv;
    int s0 = __builtin_amdgcn_readfirstlane(src_perm[j]);
    acc0 = fmaf(a0, xl[(size_t)s0 * D + lane], acc0);
  }
  out[row * D + lane] = acc0 + acc1 + bias[lane];
}

static inline char* align_up(char* p, size_t a) {
  return (char*)(((uintptr_t)p + a - 1) & ~(uintptr_t)(a - 1));
}

extern "C" void kernel_launch(void* const* d_in, const int* in_sizes, int n_in,
                              void* d_out, int out_size, void* d_ws, size_t ws_size,
                              hipStream_t stream) {
  const float* x   = (const float*)d_in[0];
  const int* ei    = (const int*)d_in[1];   // harness passes integer inputs as int32 (validated R2)
  const float* ea  = (const float*)d_in[2];
  const float* Wl  = (const float*)d_in[3];
  const float* bl  = (const float*)d_in[4];
  const float* Wr  = (const float*)d_in[5];
  const float* br  = (const float*)d_in[6];
  const float* We  = (const float*)d_in[7];
  const float* att = (const float*)d_in[8];
  const float* bias = (const float*)d_in[9];
  float* out = (float*)d_out;

  // workspace carve-up (~42 MB), 256B-aligned blocks
  char* w = (char*)d_ws;
  float* xl       = (float*)w; w = align_up(w + (size_t)N_NODES * D * 4, 256);
  float* xr       = (float*)w; w = align_up(w + (size_t)N_NODES * D * 4, 256);
  float* logits   = (float*)w; w = align_up(w + (size_t)N_EDGES * 4, 256);
  float* plog     = (float*)w; w = align_up(w + (size_t)N_EDGES * 4, 256);
  int* row_start  = (int*)w;   w = align_up(w + (size_t)(N_NODES + 1) * 4, 256);
  int* cursor     = (int*)w;   w = align_up(w + (size_t)N_NODES * 4, 256);
  int* bsum       = (int*)w;   w = align_up(w + 256 * 4, 256);
  int* eid_perm   = (int*)w;   w = align_up(w + (size_t)N_EDGES * 4, 256);
  int* src_perm   = (int*)w;   w = align_up(w + (size_t)N_EDGES * 4, 256);

  const int NB = (N_NODES + 255) / 256;  // 196

  k_init<<<NB, 256, 0, stream>>>(cursor);
  k_transform<<<N_NODES / 4, 256, 0, stream>>>(x, Wl, bl, Wr, br, xl, xr);
  k_logits<<<N_EDGES / 4, 256, 0, stream>>>(ea, We, att, xl, xr, ei, logits);
  k_hist<<<(N_EDGES + 255) / 256, 256, 0, stream>>>(ei, cursor);
  k_scan_a<<<NB, 256, 0, stream>>>(cursor, row_start, bsum);
  k_scan_b<<<1, 256, 0, stream>>>(bsum, NB);
  k_scan_c<<<NB, 256, 0, stream>>>(row_start, bsum, cursor);
  k_scatter<<<(N_EDGES + 255) / 256, 256, 0, stream>>>(ei, cursor, eid_perm, src_perm);
  k_permlog<<<(N_EDGES + 255) / 256, 256, 0, stream>>>(logits, eid_perm, plog);
  k_agg<<<(N_NODES + 3) / 4, 256, 0, stream>>>(plog, row_start, src_perm, xl, bias, out);
}

// Round 13
// 536.523 us; speedup vs baseline: 1.3782x; 1.3782x over previous
//
#include <hip/hip_runtime.h>
#include <hip/hip_bf16.h>
#include <math.h>

#define N_NODES 50000
#define N_EDGES 1000000
#define D 64
#define ED 16
#define NEG 0.2f

__device__ __forceinline__ float wave_sum(float v) {
  #pragma unroll
  for (int m = 32; m >= 1; m >>= 1) v += __shfl_xor(v, m, 64);
  return v;
}

// ---- zero the histogram counters ----
__global__ void k_init(int* __restrict__ cursor) {
  int i = blockIdx.x * 256 + threadIdx.x;
  if (i < N_NODES) cursor[i] = 0;
}

// ---- x_l = x@Wl + bl (stored bf16 for cheap gathers); x_r = x@Wr + br (fp32) ----
__global__ __launch_bounds__(256) void k_transform(
    const float* __restrict__ x,
    const float* __restrict__ Wl, const float* __restrict__ bl,
    const float* __restrict__ Wr, const float* __restrict__ br,
    __hip_bfloat16* __restrict__ xlb, float* __restrict__ xr) {
  __shared__ float sW[2 * D * D];  // 32 KiB
  float* sWl = sW;
  float* sWr = sW + D * D;
  int t = threadIdx.x;
  for (int q = t; q < D * D / 4; q += 256) {
    ((float4*)sWl)[q] = ((const float4*)Wl)[q];
    ((float4*)sWr)[q] = ((const float4*)Wr)[q];
  }
  __syncthreads();
  int lane = t & 63;
  int row = blockIdx.x * 4 + (t >> 6);
  if (row >= N_NODES) return;
  float xv = x[row * D + lane];
  float accl = bl[lane], accr = br[lane];
  #pragma unroll
  for (int k = 0; k < D; k++) {
    float xk = __shfl(xv, k, 64);
    accl = fmaf(xk, sWl[k * D + lane], accl);
    accr = fmaf(xk, sWr[k * D + lane], accr);
  }
  xlb[row * D + lane] = __float2bfloat16(accl);
  xr[row * D + lane] = accr;
}

// ---- histogram of dst (validated) ----
__global__ void k_hist(const int* __restrict__ ei, int* __restrict__ cursor) {
  int e = blockIdx.x * 256 + threadIdx.x;
  if (e < N_EDGES) atomicAdd(&cursor[ei[N_EDGES + e]], 1);
}

// ---- 3-kernel exclusive scan of counts -> row_start (validated) ----
__global__ void k_scan_a(const int* __restrict__ counts, int* __restrict__ row_start,
                         int* __restrict__ bsum) {
  __shared__ int sb[256];
  int t = threadIdx.x;
  int i = blockIdx.x * 256 + t;
  int v = (i < N_NODES) ? counts[i] : 0;
  sb[t] = v;
  __syncthreads();
  for (int off = 1; off < 256; off <<= 1) {
    int add = (t >= off) ? sb[t - off] : 0;
    __syncthreads();
    sb[t] += add;
    __syncthreads();
  }
  if (i < N_NODES) row_start[i] = sb[t] - v;  // exclusive
  if (t == 255) bsum[blockIdx.x] = sb[t];
}
__global__ void k_scan_b(int* __restrict__ bsum, int nb) {
  __shared__ int sb[256];
  int t = threadIdx.x;
  int v = (t < nb) ? bsum[t] : 0;
  sb[t] = v;
  __syncthreads();
  for (int off = 1; off < 256; off <<= 1) {
    int add = (t >= off) ? sb[t - off] : 0;
    __syncthreads();
    sb[t] += add;
    __syncthreads();
  }
  if (t < nb) bsum[t] = sb[t] - v;  // exclusive
}
__global__ void k_scan_c(int* __restrict__ row_start, const int* __restrict__ bsum,
                         int* __restrict__ cursor) {
  int t = threadIdx.x;
  int i = blockIdx.x * 256 + t;
  if (i < N_NODES) {
    int r = row_start[i] + bsum[blockIdx.x];
    row_start[i] = r;
    cursor[i] = r;
  }
  if (i == 0) row_start[N_NODES] = N_EDGES;
}

// ---- counting-sort scatter: slot assignment per edge (validated R9 form) ----
__global__ void k_scatter(const int* __restrict__ ei, int* __restrict__ cursor,
                          int* __restrict__ eid_perm, int* __restrict__ src_perm) {
  int e = blockIdx.x * 256 + threadIdx.x;
  if (e >= N_EDGES) return;
  int s = ei[e];
  int d = ei[N_EDGES + e];
  int pos = atomicAdd(&cursor[d], 1);
  eid_perm[pos] = e;
  src_perm[pos] = s;
}

// ---- fused per-node online-softmax attention + aggregation (wave per node) ----
// Each edge's xl[src] row is gathered ONCE and reused for logit + accumulation.
__global__ __launch_bounds__(256) void k_fused(
    const float* __restrict__ ea, const float* __restrict__ We,
    const float* __restrict__ att,
    const __hip_bfloat16* __restrict__ xlb, const float* __restrict__ xr,
    const int* __restrict__ row_start, const int* __restrict__ eid_perm,
    const int* __restrict__ src_perm, const float* __restrict__ bias,
    float* __restrict__ out) {
  __shared__ float sWe[ED * D];  // 4 KiB
  __shared__ float satt[D];
  int t = threadIdx.x;
  for (int q = t; q < ED * D / 4; q += 256) ((float4*)sWe)[q] = ((const float4*)We)[q];
  if (t < D) satt[t] = att[t];
  __syncthreads();
  int lane = t & 63;
  int n = blockIdx.x * 4 + (t >> 6);
  if (n >= N_NODES) return;
  int start = row_start[n];
  int end = row_start[n + 1];

  float xrv = xr[(size_t)n * D + lane];  // one linear row read per node
  float av = satt[lane];
  float m = -INFINITY, lsum = 0.f, O = 0.f;

  for (int i = start; i < end; ++i) {
    // i is wave-uniform; values are wave-uniform (all lanes load same addr)
    int e = __builtin_amdgcn_readfirstlane(eid_perm[i]);
    int s = __builtin_amdgcn_readfirstlane(src_perm[i]);
    // the two random gathers for this edge (independent of the online chain,
    // so the compiler can hoist the next iteration's loads under this one)
    float xlv = __bfloat162float(xlb[(size_t)s * D + lane]);  // 128 B row
    float eav = (lane < ED) ? ea[(size_t)e * ED + lane] : 0.f; // 64 B row
    float acc = 0.f;
    #pragma unroll
    for (int k = 0; k < ED; k++) {
      float ek = __shfl(eav, k, 64);
      acc = fmaf(ek, sWe[k * D + lane], acc);
    }
    float h = xlv + xrv + acc;
    h = (h > 0.f) ? h : NEG * h;
    float logit = wave_sum(h * av);  // all lanes hold the logit
    // online softmax update
    float mn = fmaxf(m, logit);
    float sc = __expf(m - mn);       // first iter: exp(-inf)=0
    float p = __expf(logit - mn);
    lsum = fmaf(lsum, sc, p);
    O = O * sc + p * xlv;
    m = mn;
  }
  out[(size_t)n * D + lane] = O / (lsum + 1e-16f) + bias[lane];
}

static inline char* align_up(char* p, size_t a) {
  return (char*)(((uintptr_t)p + a - 1) & ~(uintptr_t)(a - 1));
}

extern "C" void kernel_launch(void* const* d_in, const int* in_sizes, int n_in,
                              void* d_out, int out_size, void* d_ws, size_t ws_size,
                              hipStream_t stream) {
  const float* x   = (const float*)d_in[0];
  const int* ei    = (const int*)d_in[1];   // harness passes integer inputs as int32 (validated)
  const float* ea  = (const float*)d_in[2];
  const float* Wl  = (const float*)d_in[3];
  const float* bl  = (const float*)d_in[4];
  const float* Wr  = (const float*)d_in[5];
  const float* br  = (const float*)d_in[6];
  const float* We  = (const float*)d_in[7];
  const float* att = (const float*)d_in[8];
  const float* bias = (const float*)d_in[9];
  float* out = (float*)d_out;

  // workspace carve-up (~28 MB), 256B-aligned blocks
  char* w = (char*)d_ws;
  __hip_bfloat16* xlb = (__hip_bfloat16*)w; w = align_up(w + (size_t)N_NODES * D * 2, 256);
  float* xr       = (float*)w; w = align_up(w + (size_t)N_NODES * D * 4, 256);
  int* row_start  = (int*)w;   w = align_up(w + (size_t)(N_NODES + 1) * 4, 256);
  int* cursor     = (int*)w;   w = align_up(w + (size_t)N_NODES * 4, 256);
  int* bsum       = (int*)w;   w = align_up(w + 256 * 4, 256);
  int* eid_perm   = (int*)w;   w = align_up(w + (size_t)N_EDGES * 4, 256);
  int* src_perm   = (int*)w;   w = align_up(w + (size_t)N_EDGES * 4, 256);

  const int NB = (N_NODES + 255) / 256;  // 196

  k_init<<<NB, 256, 0, stream>>>(cursor);
  k_transform<<<N_NODES / 4, 256, 0, stream>>>(x, Wl, bl, Wr, br, xlb, xr);
  k_hist<<<(N_EDGES + 255) / 256, 256, 0, stream>>>(ei, cursor);
  k_scan_a<<<NB, 256, 0, stream>>>(cursor, row_start, bsum);
  k_scan_b<<<1, 256, 0, stream>>>(bsum, NB);
  k_scan_c<<<NB, 256, 0, stream>>>(row_start, bsum, cursor);
  k_scatter<<<(N_EDGES + 255) / 256, 256, 0, stream>>>(ei, cursor, eid_perm, src_perm);
  k_fused<<<(N_NODES + 3) / 4, 256, 0, stream>>>(ea, We, att, xlb, xr, row_start,
                                                 eid_perm, src_perm, bias, out);
}